// Round 1
// baseline (829.915 us; speedup 1.0000x reference)
//
#include <hip/hip_runtime.h>
#include <cstdint>
#include <cstddef>

#define NN   20000
#define NPAD 20032
#define EE   640000
#define E2   660000   // EE + NN self loops
#define HHD  4
#define CC   64
#define HC   256
#define NEG  0.2f

__device__ __forceinline__ float sigmoidf_(float x) { return 1.0f / (1.0f + __expf(-x)); }

__device__ __forceinline__ float wred_sum(float v) {
#pragma unroll
    for (int d = 32; d; d >>= 1) v += __shfl_xor(v, d, 64);
    return v;
}

// ---------------- CSR build ----------------
__global__ void zero_cnt(int* cnt) {
    int i = blockIdx.x * 256 + threadIdx.x;
    if (i < NN) cnt[i] = 0;
}

__global__ void count_edges(const int* __restrict__ ei, int* __restrict__ cnt) {
    int e = blockIdx.x * 256 + threadIdx.x;
    if (e < E2) {
        int d = (e < EE) ? ei[EE + e] : (e - EE);
        atomicAdd(&cnt[d], 1);
    }
}

__global__ __launch_bounds__(1024) void scan_off(const int* __restrict__ cnt,
                                                 int* __restrict__ off,
                                                 int* __restrict__ cur) {
    __shared__ int buf[1024];
    __shared__ int carry;
    int tid = threadIdx.x;
    if (tid == 0) carry = 0;
    __syncthreads();
    for (int base = 0; base < NN; base += 1024) {
        int i = base + tid;
        int v = (i < NN) ? cnt[i] : 0;
        buf[tid] = v;
        __syncthreads();
        for (int d = 1; d < 1024; d <<= 1) {
            int t = (tid >= d) ? buf[tid - d] : 0;
            __syncthreads();
            buf[tid] += t;
            __syncthreads();
        }
        int excl = buf[tid] - v;
        int ctot = buf[1023];
        if (i < NN) { off[i] = carry + excl; cur[i] = carry + excl; }
        __syncthreads();
        if (tid == 0) carry += ctot;
        __syncthreads();
    }
    if (tid == 0) off[NN] = carry;
}

__global__ void scatter_edges(const int* __restrict__ ei, int* __restrict__ cur,
                              int* __restrict__ csr) {
    int e = blockIdx.x * 256 + threadIdx.x;
    if (e < E2) {
        int s, d;
        if (e < EE) { s = ei[e]; d = ei[EE + e]; }
        else        { s = e - EE; d = s; }
        int p = atomicAdd(&cur[d], 1);
        csr[p] = s;
    }
}

// ---------------- fp32 tiled GEMM: Out[n, OUT] = A[n, IN] @ W[IN, OUT] ----------------
// 64 nodes x 64 channels per 256-thread block, 4x4 register tile per thread.
template <int IN_CH, int OUT_CH, bool RELU, bool BIAS>
__global__ __launch_bounds__(256) void gemm_tile(const float* __restrict__ A,
                                                 const float* __restrict__ W,
                                                 const float* __restrict__ bias,
                                                 float* __restrict__ Out, int nreal) {
    __shared__ float As[64][68];   // stride 68: 16B-aligned rows, 2-way-max bank alias (free)
    const int tid = threadIdx.x;
    const int tx = tid & 15, ty = tid >> 4;
    const int mb = blockIdx.x * 64;
    const int c0 = blockIdx.y * 64 + tx * 4;

    float acc[4][4];
#pragma unroll
    for (int j = 0; j < 4; j++)
#pragma unroll
        for (int q = 0; q < 4; q++) acc[j][q] = 0.0f;

    const int lm = tid >> 4;          // load row base 0..15
    const int lk = (tid & 15) * 4;    // load k offset

    for (int kc = 0; kc < IN_CH; kc += 64) {
#pragma unroll
        for (int r = 0; r < 4; r++) {
            int m = lm + r * 16;
            int row = mb + m;
            float4 v = make_float4(0.f, 0.f, 0.f, 0.f);
            if (row < nreal) v = *(const float4*)&A[(size_t)row * IN_CH + kc + lk];
            *(float4*)&As[m][lk] = v;
        }
        __syncthreads();
#pragma unroll 8
        for (int k = 0; k < 64; k++) {
            float4 w4 = *(const float4*)&W[(kc + k) * OUT_CH + c0];
#pragma unroll
            for (int j = 0; j < 4; j++) {
                float a = As[ty * 4 + j][k];
                acc[j][0] += a * w4.x;
                acc[j][1] += a * w4.y;
                acc[j][2] += a * w4.z;
                acc[j][3] += a * w4.w;
            }
        }
        __syncthreads();
    }

#pragma unroll
    for (int j = 0; j < 4; j++) {
        int row = mb + ty * 4 + j;
        float4 v = make_float4(acc[j][0], acc[j][1], acc[j][2], acc[j][3]);
        if (BIAS) {
            v.x += bias[c0];     v.y += bias[c0 + 1];
            v.z += bias[c0 + 2]; v.w += bias[c0 + 3];
        }
        if (RELU) {
            v.x = fmaxf(v.x, 0.f); v.y = fmaxf(v.y, 0.f);
            v.z = fmaxf(v.z, 0.f); v.w = fmaxf(v.w, 0.f);
        }
        *(float4*)&Out[(size_t)row * OUT_CH + c0] = v;   // Out is NPAD-padded
    }
}

// ---------------- attention scores: s_src/s_dst (N, 4) ----------------
__global__ __launch_bounds__(256) void attn_scores(const float* __restrict__ hh,
                                                   const float* __restrict__ a_src,
                                                   const float* __restrict__ a_dst,
                                                   float* __restrict__ s_src,
                                                   float* __restrict__ s_dst) {
    int node = blockIdx.x * 4 + (threadIdx.x >> 6);
    int lane = threadIdx.x & 63;
    int head = lane >> 4, q = lane & 15;
    const float* hrow = hh + (size_t)node * HC + head * 64 + q * 4;
    float4 hv = *(const float4*)hrow;
    float4 av = *(const float4*)(a_src + head * 64 + q * 4);
    float4 dv = *(const float4*)(a_dst + head * 64 + q * 4);
    float ls = hv.x * av.x + hv.y * av.y + hv.z * av.z + hv.w * av.w;
    float ld = hv.x * dv.x + hv.y * dv.y + hv.z * dv.z + hv.w * dv.w;
#pragma unroll
    for (int d = 8; d; d >>= 1) {
        ls += __shfl_xor(ls, d, 64);
        ld += __shfl_xor(ld, d, 64);
    }
    if (q == 0) {
        s_src[node * 4 + head] = ls;
        s_dst[node * 4 + head] = ld;
    }
}

// ---------------- per-dst-node GAT aggregation (one wave per node) ----------------
__global__ __launch_bounds__(64) void gat_node(const float* __restrict__ hh,
                                               const float* __restrict__ s_src,
                                               const float* __restrict__ s_dst,
                                               const int* __restrict__ csr_src,
                                               const int* __restrict__ csr_off,
                                               const float* __restrict__ gbias,
                                               const float* __restrict__ conf_w,
                                               const float* __restrict__ conf_b,
                                               const float* __restrict__ confid,
                                               float* __restrict__ h, int layer) {
    int n = blockIdx.x;
    int lane = threadIdx.x;
    int off0 = csr_off[n];
    int deg = csr_off[n + 1] - off0;

    float4 sd4 = *(const float4*)&s_dst[n * 4];
    float sdh[4] = {sd4.x, sd4.y, sd4.z, sd4.w};

    // pass 1: per-head max over incoming edges
    float mx[4] = {-1e30f, -1e30f, -1e30f, -1e30f};
    for (int e = lane; e < deg; e += 64) {
        int s = csr_src[off0 + e];
        float4 ss = *(const float4*)&s_src[s * 4];
        float a0 = ss.x + sdh[0]; a0 = a0 > 0.f ? a0 : NEG * a0; mx[0] = fmaxf(mx[0], a0);
        float a1 = ss.y + sdh[1]; a1 = a1 > 0.f ? a1 : NEG * a1; mx[1] = fmaxf(mx[1], a1);
        float a2 = ss.z + sdh[2]; a2 = a2 > 0.f ? a2 : NEG * a2; mx[2] = fmaxf(mx[2], a2);
        float a3 = ss.w + sdh[3]; a3 = a3 > 0.f ? a3 : NEG * a3; mx[3] = fmaxf(mx[3], a3);
    }
#pragma unroll
    for (int d = 32; d; d >>= 1) {
#pragma unroll
        for (int hd = 0; hd < 4; hd++) mx[hd] = fmaxf(mx[hd], __shfl_xor(mx[hd], d, 64));
    }

    // pass 2: per-head exp-sum
    float sm[4] = {0.f, 0.f, 0.f, 0.f};
    for (int e = lane; e < deg; e += 64) {
        int s = csr_src[off0 + e];
        float4 ss = *(const float4*)&s_src[s * 4];
        float a0 = ss.x + sdh[0]; a0 = a0 > 0.f ? a0 : NEG * a0; sm[0] += __expf(a0 - mx[0]);
        float a1 = ss.y + sdh[1]; a1 = a1 > 0.f ? a1 : NEG * a1; sm[1] += __expf(a1 - mx[1]);
        float a2 = ss.z + sdh[2]; a2 = a2 > 0.f ? a2 : NEG * a2; sm[2] += __expf(a2 - mx[2]);
        float a3 = ss.w + sdh[3]; a3 = a3 > 0.f ? a3 : NEG * a3; sm[3] += __expf(a3 - mx[3]);
    }
#pragma unroll
    for (int d = 32; d; d >>= 1) {
#pragma unroll
        for (int hd = 0; hd < 4; hd++) sm[hd] += __shfl_xor(sm[hd], d, 64);
    }
    float inv[4];
#pragma unroll
    for (int hd = 0; hd < 4; hd++) inv[hd] = 1.0f / fmaxf(sm[hd], 1e-16f);

    // pass 3: weighted gather-accumulate; lane owns channels 4*lane..4*lane+3
    int myhead = lane >> 4;
    float sdm = sdh[myhead], mxm = mx[myhead], invm = inv[myhead];
    float ax = 0.f, ay = 0.f, az = 0.f, aw = 0.f;
    for (int e = 0; e < deg; e++) {
        int s = csr_src[off0 + e];
        float a = s_src[s * 4 + myhead] + sdm;
        a = a > 0.f ? a : NEG * a;
        float coef = __expf(a - mxm) * invm;
        float4 v = *(const float4*)&hh[(size_t)s * HC + lane * 4];
        ax += coef * v.x; ay += coef * v.y; az += coef * v.z; aw += coef * v.w;
    }

    // epilogue: bias, confidence gate, residual, relu
    float4 b4 = *(const float4*)&gbias[lane * 4];
    float hx = ax + b4.x, hy = ay + b4.y, hz = az + b4.z, hw = aw + b4.w;
    float4 cw4 = *(const float4*)&conf_w[lane * 4];
    float local = hx * cw4.x + hy * cw4.y + hz * cw4.z + hw * cw4.w;
    float tot = wred_sum(local);
    float cw = sigmoidf_(tot + conf_b[0]) * sigmoidf_(confid[n]);
    hx *= cw; hy *= cw; hz *= cw; hw *= cw;
    if (layer > 0) {
        float4 hp = *(const float4*)&h[(size_t)n * HC + lane * 4];
        hx += hp.x; hy += hp.y; hz += hp.z; hw += hp.w;
    }
    if (layer < 2) {
        hx = fmaxf(hx, 0.f); hy = fmaxf(hy, 0.f);
        hz = fmaxf(hz, 0.f); hw = fmaxf(hw, 0.f);
    }
    *(float4*)&h[(size_t)n * HC + lane * 4] = make_float4(hx, hy, hz, hw);
}

// ---------------- pack the 3 head W1/b1 into one (256,192) GEMM ----------------
__global__ void repack_heads(const float* __restrict__ nc1, const float* __restrict__ oc1,
                             const float* __restrict__ ec1, const float* __restrict__ nb,
                             const float* __restrict__ ob, const float* __restrict__ eb,
                             float* __restrict__ Wcat, float* __restrict__ bcat) {
    int idx = blockIdx.x * 256 + threadIdx.x;
    if (idx < 256 * 192) {
        int k = idx / 192, j = idx % 192;
        int g = j >> 6, jj = j & 63;
        const float* w = (g == 0) ? nc1 : ((g == 1) ? oc1 : ec1);
        Wcat[idx] = w[k * 64 + jj];
    }
    if (idx < 192) {
        int g = idx >> 6, jj = idx & 63;
        const float* b = (g == 0) ? nb : ((g == 1) ? ob : eb);
        bcat[idx] = b[jj];
    }
}

// ---------------- final heads + h copy-out ----------------
__global__ __launch_bounds__(64) void head_final(const float* __restrict__ T,
                                                 const float* __restrict__ h,
                                                 const float* __restrict__ nc_w2,
                                                 const float* __restrict__ nc_b2,
                                                 const float* __restrict__ oc_w2,
                                                 const float* __restrict__ oc_b2,
                                                 const float* __restrict__ ec_w2,
                                                 const float* __restrict__ ec_b2,
                                                 float* __restrict__ out) {
    int n = blockIdx.x, lane = threadIdx.x;
    float t0 = T[(size_t)n * 192 + lane];
    float t1 = T[(size_t)n * 192 + 64 + lane];
    float t2 = T[(size_t)n * 192 + 128 + lane];
    float pn = wred_sum(t0 * nc_w2[lane]);
    float po = wred_sum(t1 * oc_w2[lane]);
    float4 ew = *(const float4*)&ec_w2[lane * 4];
    float e0 = wred_sum(t2 * ew.x);
    float e1 = wred_sum(t2 * ew.y);
    float e2 = wred_sum(t2 * ew.z);
    float e3 = wred_sum(t2 * ew.w);
    if (lane == 0) {
        out[n] = sigmoidf_(pn + nc_b2[0]);
        out[NN + n] = sigmoidf_(po + oc_b2[0]);
        float4 ev = make_float4(e0 + ec_b2[0], e1 + ec_b2[1], e2 + ec_b2[2], e3 + ec_b2[3]);
        *(float4*)&out[2 * NN + n * 4] = ev;
    }
    float4 hv = *(const float4*)&h[(size_t)n * HC + lane * 4];
    *(float4*)&out[6 * NN + (size_t)n * HC + lane * 4] = hv;
}

extern "C" void kernel_launch(void* const* d_in, const int* in_sizes, int n_in,
                              void* d_out, int out_size, void* d_ws, size_t ws_size,
                              hipStream_t stream) {
    const float* x       = (const float*)d_in[0];
    const int*   ei      = (const int*)d_in[1];
    const float* conf    = (const float*)d_in[2];
    const float* w_in    = (const float*)d_in[3];
    const float* b_in    = (const float*)d_in[4];
    const float* lin_w0  = (const float*)d_in[5];
    const float* lin_w12 = (const float*)d_in[6];
    const float* att_src = (const float*)d_in[7];
    const float* att_dst = (const float*)d_in[8];
    const float* gbias   = (const float*)d_in[9];
    const float* conf_w  = (const float*)d_in[10];
    const float* conf_b  = (const float*)d_in[11];
    const float* nc_w1   = (const float*)d_in[12];
    const float* nc_b1   = (const float*)d_in[13];
    const float* nc_w2   = (const float*)d_in[14];
    const float* nc_b2   = (const float*)d_in[15];
    const float* oc_w1   = (const float*)d_in[16];
    const float* oc_b1   = (const float*)d_in[17];
    const float* oc_w2   = (const float*)d_in[18];
    const float* oc_b2   = (const float*)d_in[19];
    const float* ec_w1   = (const float*)d_in[20];
    const float* ec_b1   = (const float*)d_in[21];
    const float* ec_w2   = (const float*)d_in[22];
    const float* ec_b2   = (const float*)d_in[23];
    float* out = (float*)d_out;

    char* p = (char*)d_ws;
    auto alloc = [&](size_t bytes) -> void* {
        void* r = (void*)p;
        p += (bytes + 255) & ~(size_t)255;
        return r;
    };
    float* h0   = (float*)alloc((size_t)NPAD * 64 * 4);
    float* h    = (float*)alloc((size_t)NPAD * HC * 4);
    float* hh   = (float*)alloc((size_t)NPAD * HC * 4);
    float* ssrc = (float*)alloc((size_t)NN * 4 * 4);
    float* sdst = (float*)alloc((size_t)NN * 4 * 4);
    int*   cnt  = (int*)alloc((size_t)NN * 4);
    int*   off  = (int*)alloc((size_t)(NN + 1) * 4);
    int*   cur  = (int*)alloc((size_t)NN * 4);
    int*   csr  = (int*)alloc((size_t)E2 * 4);
    float* Wcat = (float*)alloc((size_t)256 * 192 * 4);
    float* bcat = (float*)alloc((size_t)192 * 4);
    float* Tbuf = hh;  // reuse hh after last GAT layer

    // CSR by dst (with self loops appended)
    zero_cnt<<<(NN + 255) / 256, 256, 0, stream>>>(cnt);
    count_edges<<<(E2 + 255) / 256, 256, 0, stream>>>(ei, cnt);
    scan_off<<<1, 1024, 0, stream>>>(cnt, off, cur);
    scatter_edges<<<(E2 + 255) / 256, 256, 0, stream>>>(ei, cur, csr);

    // input projection + relu: h0 = relu(x @ w_in + b_in)   (N,256)->(N,64)
    gemm_tile<256, 64, true, true><<<dim3(NPAD / 64, 1), 256, 0, stream>>>(x, w_in, b_in, h0, NN);

    // GAT layer 0 (in=64)
    gemm_tile<64, 256, false, false><<<dim3(NPAD / 64, 4), 256, 0, stream>>>(h0, lin_w0, nullptr, hh, NN);
    attn_scores<<<NN / 4, 256, 0, stream>>>(hh, att_src, att_dst, ssrc, sdst);
    gat_node<<<NN, 64, 0, stream>>>(hh, ssrc, sdst, csr, off, gbias, conf_w, conf_b, conf, h, 0);

    // GAT layers 1,2 (in=256)
    for (int i = 1; i < 3; i++) {
        gemm_tile<256, 256, false, false><<<dim3(NPAD / 64, 4), 256, 0, stream>>>(
            h, lin_w12 + (size_t)(i - 1) * HC * HC, nullptr, hh, NN);
        attn_scores<<<NN / 4, 256, 0, stream>>>(hh, att_src + i * HHD * CC, att_dst + i * HHD * CC, ssrc, sdst);
        gat_node<<<NN, 64, 0, stream>>>(hh, ssrc, sdst, csr, off, gbias + i * HC, conf_w, conf_b, conf, h, i);
    }

    // heads: T = relu(h @ [nc_w1|oc_w1|ec_w1] + b)   (N,192)
    repack_heads<<<(256 * 192 + 255) / 256, 256, 0, stream>>>(nc_w1, oc_w1, ec_w1, nc_b1, oc_b1, ec_b1, Wcat, bcat);
    gemm_tile<256, 192, true, true><<<dim3(NPAD / 64, 3), 256, 0, stream>>>(h, Wcat, bcat, Tbuf, NN);
    head_final<<<NN, 64, 0, stream>>>(Tbuf, h, nc_w2, nc_b2, oc_w2, oc_b2, ec_w2, ec_b2, out);
}

// Round 2
// 683.098 us; speedup vs baseline: 1.2149x; 1.2149x over previous
//
#include <hip/hip_runtime.h>
#include <cstdint>
#include <cstddef>

#define NN   20000
#define NPAD 20096   // 157*128
#define EE   640000
#define E2   660000   // EE + NN self loops
#define HHD  4
#define CC   64
#define HC   256
#define NEG  0.2f

__device__ __forceinline__ float sigmoidf_(float x) { return 1.0f / (1.0f + __expf(-x)); }

__device__ __forceinline__ float wred_sum(float v) {
#pragma unroll
    for (int d = 32; d; d >>= 1) v += __shfl_xor(v, d, 64);
    return v;
}

// ---------------- CSR build ----------------
__global__ void zero_cnt(int* cnt) {
    int i = blockIdx.x * 256 + threadIdx.x;
    if (i < NN) cnt[i] = 0;
}

__global__ void count_edges(const int* __restrict__ ei, int* __restrict__ cnt) {
    int e = blockIdx.x * 256 + threadIdx.x;
    if (e < E2) {
        int d = (e < EE) ? ei[EE + e] : (e - EE);
        atomicAdd(&cnt[d], 1);
    }
}

// single block, 1024 threads; each thread owns 20 contiguous counts.
__global__ __launch_bounds__(1024) void scan_off(const int* __restrict__ cnt,
                                                 int* __restrict__ off,
                                                 int* __restrict__ cur) {
    __shared__ int buf[1024];
    int t = threadIdx.x;
    int base = t * 20;
    int local[20];
    int s = 0;
#pragma unroll
    for (int i = 0; i < 20; i++) {
        int idx = base + i;
        int v = (idx < NN) ? cnt[idx] : 0;
        local[i] = v;
        s += v;
    }
    buf[t] = s;
    __syncthreads();
    for (int d = 1; d < 1024; d <<= 1) {
        int tv = (t >= d) ? buf[t - d] : 0;
        __syncthreads();
        buf[t] += tv;
        __syncthreads();
    }
    int run = buf[t] - s;  // exclusive prefix of this thread's chunk
#pragma unroll
    for (int i = 0; i < 20; i++) {
        int idx = base + i;
        if (idx < NN) { off[idx] = run; cur[idx] = run; }
        run += local[i];
    }
    if (t == 1023) off[NN] = buf[1023];
}

__global__ void scatter_edges(const int* __restrict__ ei, int* __restrict__ cur,
                              int* __restrict__ csr) {
    int e = blockIdx.x * 256 + threadIdx.x;
    if (e < E2) {
        int s, d;
        if (e < EE) { s = ei[e]; d = ei[EE + e]; }
        else        { s = e - EE; d = s; }
        int p = atomicAdd(&cur[d], 1);
        csr[p] = s;
    }
}

// ---------------- fp32 tiled GEMM: Out[n, OUT] = A[n, IN] @ W[IN, OUT] ----------------
// TM rows x 64 cols per 256-thread block; both A and W tiles staged in LDS;
// A read along k via float4 (ds_read_b128, broadcast across the 16 col lanes).
template <int IN_CH, int OUT_CH, int TM, bool RELU, bool BIAS>
__global__ __launch_bounds__(256) void gemm_tile(const float* __restrict__ A,
                                                 const float* __restrict__ W,
                                                 const float* __restrict__ bias,
                                                 float* __restrict__ Out, int nreal) {
    constexpr int R = TM / 16;                  // rows per thread
    __shared__ float As[TM][68];
    __shared__ float Ws[64][68];
    const int tid = threadIdx.x;
    const int tx = tid & 15, tm = tid >> 4;
    const int mb = blockIdx.x * TM;
    const int cb = blockIdx.y * 64;
    const int c0 = cb + tx * 4;

    float acc[R][4];
#pragma unroll
    for (int j = 0; j < R; j++)
#pragma unroll
        for (int q = 0; q < 4; q++) acc[j][q] = 0.0f;

    for (int kc = 0; kc < IN_CH; kc += 64) {
        // stage A tile: R float4 per thread
#pragma unroll
        for (int i = 0; i < R; i++) {
            int f = tid + i * 256;
            int r = f >> 4;
            int kq = (f & 15) * 4;
            int row = mb + r;
            float4 v = make_float4(0.f, 0.f, 0.f, 0.f);
            if (row < nreal) v = *(const float4*)&A[(size_t)row * IN_CH + kc + kq];
            *(float4*)&As[r][kq] = v;
        }
        // stage W tile: 4 float4 per thread
#pragma unroll
        for (int i = 0; i < 4; i++) {
            int f = tid + i * 256;
            int r = f >> 4;
            int wc = (f & 15) * 4;
            *(float4*)&Ws[r][wc] = *(const float4*)&W[(size_t)(kc + r) * OUT_CH + cb + wc];
        }
        __syncthreads();
#pragma unroll 4
        for (int k4 = 0; k4 < 64; k4 += 4) {
            float4 w0 = *(const float4*)&Ws[k4 + 0][tx * 4];
            float4 w1 = *(const float4*)&Ws[k4 + 1][tx * 4];
            float4 w2 = *(const float4*)&Ws[k4 + 2][tx * 4];
            float4 w3 = *(const float4*)&Ws[k4 + 3][tx * 4];
#pragma unroll
            for (int j = 0; j < R; j++) {
                float4 a = *(const float4*)&As[tm * R + j][k4];
                acc[j][0] += a.x * w0.x + a.y * w1.x + a.z * w2.x + a.w * w3.x;
                acc[j][1] += a.x * w0.y + a.y * w1.y + a.z * w2.y + a.w * w3.y;
                acc[j][2] += a.x * w0.z + a.y * w1.z + a.z * w2.z + a.w * w3.z;
                acc[j][3] += a.x * w0.w + a.y * w1.w + a.z * w2.w + a.w * w3.w;
            }
        }
        __syncthreads();
    }

#pragma unroll
    for (int j = 0; j < R; j++) {
        int row = mb + tm * R + j;
        float4 v = make_float4(acc[j][0], acc[j][1], acc[j][2], acc[j][3]);
        if (BIAS) {
            v.x += bias[c0];     v.y += bias[c0 + 1];
            v.z += bias[c0 + 2]; v.w += bias[c0 + 3];
        }
        if (RELU) {
            v.x = fmaxf(v.x, 0.f); v.y = fmaxf(v.y, 0.f);
            v.z = fmaxf(v.z, 0.f); v.w = fmaxf(v.w, 0.f);
        }
        *(float4*)&Out[(size_t)row * OUT_CH + c0] = v;   // Out is NPAD-padded
    }
}

// ---------------- attention scores: s_src/s_dst (N, 4) ----------------
__global__ __launch_bounds__(256) void attn_scores(const float* __restrict__ hh,
                                                   const float* __restrict__ a_src,
                                                   const float* __restrict__ a_dst,
                                                   float* __restrict__ s_src,
                                                   float* __restrict__ s_dst) {
    int node = blockIdx.x * 4 + (threadIdx.x >> 6);
    int lane = threadIdx.x & 63;
    int head = lane >> 4, q = lane & 15;
    const float* hrow = hh + (size_t)node * HC + head * 64 + q * 4;
    float4 hv = *(const float4*)hrow;
    float4 av = *(const float4*)(a_src + head * 64 + q * 4);
    float4 dv = *(const float4*)(a_dst + head * 64 + q * 4);
    float ls = hv.x * av.x + hv.y * av.y + hv.z * av.z + hv.w * av.w;
    float ld = hv.x * dv.x + hv.y * dv.y + hv.z * dv.z + hv.w * dv.w;
#pragma unroll
    for (int d = 8; d; d >>= 1) {
        ls += __shfl_xor(ls, d, 64);
        ld += __shfl_xor(ld, d, 64);
    }
    if (q == 0) {
        s_src[node * 4 + head] = ls;
        s_dst[node * 4 + head] = ld;
    }
}

// ---------------- per-dst-node GAT aggregation (one wave per node, 4 nodes/block) ----------------
__global__ __launch_bounds__(256) void gat_node(const float* __restrict__ hh,
                                                const float* __restrict__ s_src,
                                                const float* __restrict__ s_dst,
                                                const int* __restrict__ csr_src,
                                                const int* __restrict__ csr_off,
                                                const float* __restrict__ gbias,
                                                const float* __restrict__ conf_w,
                                                const float* __restrict__ conf_b,
                                                const float* __restrict__ confid,
                                                float* __restrict__ h, int layer) {
    int n = blockIdx.x * 4 + (threadIdx.x >> 6);
    int lane = threadIdx.x & 63;
    int off0 = csr_off[n];
    int deg = csr_off[n + 1] - off0;

    float4 sd4 = *(const float4*)&s_dst[n * 4];
    float sdh[4] = {sd4.x, sd4.y, sd4.z, sd4.w};

    // pass 1: per-head max over incoming edges (lane-parallel)
    float mx[4] = {-1e30f, -1e30f, -1e30f, -1e30f};
    for (int e = lane; e < deg; e += 64) {
        int s = csr_src[off0 + e];
        float4 ss = *(const float4*)&s_src[s * 4];
        float a0 = ss.x + sdh[0]; a0 = a0 > 0.f ? a0 : NEG * a0; mx[0] = fmaxf(mx[0], a0);
        float a1 = ss.y + sdh[1]; a1 = a1 > 0.f ? a1 : NEG * a1; mx[1] = fmaxf(mx[1], a1);
        float a2 = ss.z + sdh[2]; a2 = a2 > 0.f ? a2 : NEG * a2; mx[2] = fmaxf(mx[2], a2);
        float a3 = ss.w + sdh[3]; a3 = a3 > 0.f ? a3 : NEG * a3; mx[3] = fmaxf(mx[3], a3);
    }
#pragma unroll
    for (int d = 32; d; d >>= 1) {
#pragma unroll
        for (int hd = 0; hd < 4; hd++) mx[hd] = fmaxf(mx[hd], __shfl_xor(mx[hd], d, 64));
    }

    // pass 2: per-head exp-sum (lane-parallel)
    float sm[4] = {0.f, 0.f, 0.f, 0.f};
    for (int e = lane; e < deg; e += 64) {
        int s = csr_src[off0 + e];
        float4 ss = *(const float4*)&s_src[s * 4];
        float a0 = ss.x + sdh[0]; a0 = a0 > 0.f ? a0 : NEG * a0; sm[0] += __expf(a0 - mx[0]);
        float a1 = ss.y + sdh[1]; a1 = a1 > 0.f ? a1 : NEG * a1; sm[1] += __expf(a1 - mx[1]);
        float a2 = ss.z + sdh[2]; a2 = a2 > 0.f ? a2 : NEG * a2; sm[2] += __expf(a2 - mx[2]);
        float a3 = ss.w + sdh[3]; a3 = a3 > 0.f ? a3 : NEG * a3; sm[3] += __expf(a3 - mx[3]);
    }
#pragma unroll
    for (int d = 32; d; d >>= 1) {
#pragma unroll
        for (int hd = 0; hd < 4; hd++) sm[hd] += __shfl_xor(sm[hd], d, 64);
    }

    int myhead = lane >> 4;
    float sdm = sdh[myhead];
    float mxm = mx[myhead];
    float invm = 1.0f / fmaxf(sm[myhead], 1e-16f);

    // pass 3: weighted gather-accumulate; lane owns channels 4*lane..4*lane+3.
    // 4x unrolled for memory-level parallelism (4 independent gather chains).
    const int* cp = csr_src + off0;
    float ax = 0.f, ay = 0.f, az = 0.f, aw = 0.f;
    int e = 0;
    for (; e + 4 <= deg; e += 4) {
        int s0 = cp[e], s1 = cp[e + 1], s2 = cp[e + 2], s3 = cp[e + 3];
        float4 v0 = *(const float4*)&hh[(size_t)s0 * HC + lane * 4];
        float4 v1 = *(const float4*)&hh[(size_t)s1 * HC + lane * 4];
        float4 v2 = *(const float4*)&hh[(size_t)s2 * HC + lane * 4];
        float4 v3 = *(const float4*)&hh[(size_t)s3 * HC + lane * 4];
        float b0 = s_src[s0 * 4 + myhead] + sdm; b0 = b0 > 0.f ? b0 : NEG * b0;
        float b1 = s_src[s1 * 4 + myhead] + sdm; b1 = b1 > 0.f ? b1 : NEG * b1;
        float b2 = s_src[s2 * 4 + myhead] + sdm; b2 = b2 > 0.f ? b2 : NEG * b2;
        float b3 = s_src[s3 * 4 + myhead] + sdm; b3 = b3 > 0.f ? b3 : NEG * b3;
        float c0 = __expf(b0 - mxm) * invm;
        float c1 = __expf(b1 - mxm) * invm;
        float c2 = __expf(b2 - mxm) * invm;
        float c3 = __expf(b3 - mxm) * invm;
        ax += c0 * v0.x + c1 * v1.x + c2 * v2.x + c3 * v3.x;
        ay += c0 * v0.y + c1 * v1.y + c2 * v2.y + c3 * v3.y;
        az += c0 * v0.z + c1 * v1.z + c2 * v2.z + c3 * v3.z;
        aw += c0 * v0.w + c1 * v1.w + c2 * v2.w + c3 * v3.w;
    }
    for (; e < deg; e++) {
        int s = cp[e];
        float a = s_src[s * 4 + myhead] + sdm;
        a = a > 0.f ? a : NEG * a;
        float coef = __expf(a - mxm) * invm;
        float4 v = *(const float4*)&hh[(size_t)s * HC + lane * 4];
        ax += coef * v.x; ay += coef * v.y; az += coef * v.z; aw += coef * v.w;
    }

    // epilogue: bias, confidence gate, residual, relu
    float4 b4 = *(const float4*)&gbias[lane * 4];
    float hx = ax + b4.x, hy = ay + b4.y, hz = az + b4.z, hw = aw + b4.w;
    float4 cw4 = *(const float4*)&conf_w[lane * 4];
    float local = hx * cw4.x + hy * cw4.y + hz * cw4.z + hw * cw4.w;
    float tot = wred_sum(local);
    float cw = sigmoidf_(tot + conf_b[0]) * sigmoidf_(confid[n]);
    hx *= cw; hy *= cw; hz *= cw; hw *= cw;
    if (layer > 0) {
        float4 hp = *(const float4*)&h[(size_t)n * HC + lane * 4];
        hx += hp.x; hy += hp.y; hz += hp.z; hw += hp.w;
    }
    if (layer < 2) {
        hx = fmaxf(hx, 0.f); hy = fmaxf(hy, 0.f);
        hz = fmaxf(hz, 0.f); hw = fmaxf(hw, 0.f);
    }
    *(float4*)&h[(size_t)n * HC + lane * 4] = make_float4(hx, hy, hz, hw);
}

// ---------------- pack the 3 head W1/b1 into one (256,192) GEMM ----------------
__global__ void repack_heads(const float* __restrict__ nc1, const float* __restrict__ oc1,
                             const float* __restrict__ ec1, const float* __restrict__ nb,
                             const float* __restrict__ ob, const float* __restrict__ eb,
                             float* __restrict__ Wcat, float* __restrict__ bcat) {
    int idx = blockIdx.x * 256 + threadIdx.x;
    if (idx < 256 * 192) {
        int k = idx / 192, j = idx % 192;
        int g = j >> 6, jj = j & 63;
        const float* w = (g == 0) ? nc1 : ((g == 1) ? oc1 : ec1);
        Wcat[idx] = w[k * 64 + jj];
    }
    if (idx < 192) {
        int g = idx >> 6, jj = idx & 63;
        const float* b = (g == 0) ? nb : ((g == 1) ? ob : eb);
        bcat[idx] = b[jj];
    }
}

// ---------------- final heads + h copy-out ----------------
__global__ __launch_bounds__(256) void head_final(const float* __restrict__ T,
                                                  const float* __restrict__ h,
                                                  const float* __restrict__ nc_w2,
                                                  const float* __restrict__ nc_b2,
                                                  const float* __restrict__ oc_w2,
                                                  const float* __restrict__ oc_b2,
                                                  const float* __restrict__ ec_w2,
                                                  const float* __restrict__ ec_b2,
                                                  float* __restrict__ out) {
    int n = blockIdx.x * 4 + (threadIdx.x >> 6);
    int lane = threadIdx.x & 63;
    float t0 = T[(size_t)n * 192 + lane];
    float t1 = T[(size_t)n * 192 + 64 + lane];
    float t2 = T[(size_t)n * 192 + 128 + lane];
    float pn = wred_sum(t0 * nc_w2[lane]);
    float po = wred_sum(t1 * oc_w2[lane]);
    float4 ew = *(const float4*)&ec_w2[lane * 4];
    float e0 = wred_sum(t2 * ew.x);
    float e1 = wred_sum(t2 * ew.y);
    float e2 = wred_sum(t2 * ew.z);
    float e3 = wred_sum(t2 * ew.w);
    if (lane == 0) {
        out[n] = sigmoidf_(pn + nc_b2[0]);
        out[NN + n] = sigmoidf_(po + oc_b2[0]);
        float4 ev = make_float4(e0 + ec_b2[0], e1 + ec_b2[1], e2 + ec_b2[2], e3 + ec_b2[3]);
        *(float4*)&out[2 * NN + n * 4] = ev;
    }
    float4 hv = *(const float4*)&h[(size_t)n * HC + lane * 4];
    *(float4*)&out[6 * NN + (size_t)n * HC + lane * 4] = hv;
}

extern "C" void kernel_launch(void* const* d_in, const int* in_sizes, int n_in,
                              void* d_out, int out_size, void* d_ws, size_t ws_size,
                              hipStream_t stream) {
    const float* x       = (const float*)d_in[0];
    const int*   ei      = (const int*)d_in[1];
    const float* conf    = (const float*)d_in[2];
    const float* w_in    = (const float*)d_in[3];
    const float* b_in    = (const float*)d_in[4];
    const float* lin_w0  = (const float*)d_in[5];
    const float* lin_w12 = (const float*)d_in[6];
    const float* att_src = (const float*)d_in[7];
    const float* att_dst = (const float*)d_in[8];
    const float* gbias   = (const float*)d_in[9];
    const float* conf_w  = (const float*)d_in[10];
    const float* conf_b  = (const float*)d_in[11];
    const float* nc_w1   = (const float*)d_in[12];
    const float* nc_b1   = (const float*)d_in[13];
    const float* nc_w2   = (const float*)d_in[14];
    const float* nc_b2   = (const float*)d_in[15];
    const float* oc_w1   = (const float*)d_in[16];
    const float* oc_b1   = (const float*)d_in[17];
    const float* oc_w2   = (const float*)d_in[18];
    const float* oc_b2   = (const float*)d_in[19];
    const float* ec_w1   = (const float*)d_in[20];
    const float* ec_b1   = (const float*)d_in[21];
    const float* ec_w2   = (const float*)d_in[22];
    const float* ec_b2   = (const float*)d_in[23];
    float* out = (float*)d_out;

    char* p = (char*)d_ws;
    auto alloc = [&](size_t bytes) -> void* {
        void* r = (void*)p;
        p += (bytes + 255) & ~(size_t)255;
        return r;
    };
    float* h0   = (float*)alloc((size_t)NPAD * 64 * 4);
    float* h    = (float*)alloc((size_t)NPAD * HC * 4);
    float* hh   = (float*)alloc((size_t)NPAD * HC * 4);
    float* ssrc = (float*)alloc((size_t)NN * 4 * 4);
    float* sdst = (float*)alloc((size_t)NN * 4 * 4);
    int*   cnt  = (int*)alloc((size_t)NN * 4);
    int*   off  = (int*)alloc((size_t)(NN + 1) * 4);
    int*   cur  = (int*)alloc((size_t)NN * 4);
    int*   csr  = (int*)alloc((size_t)E2 * 4);
    float* Wcat = (float*)alloc((size_t)256 * 192 * 4);
    float* bcat = (float*)alloc((size_t)192 * 4);
    float* Tbuf = hh;  // reuse hh after last GAT layer

    // CSR by dst (with self loops appended)
    zero_cnt<<<(NN + 255) / 256, 256, 0, stream>>>(cnt);
    count_edges<<<(E2 + 255) / 256, 256, 0, stream>>>(ei, cnt);
    scan_off<<<1, 1024, 0, stream>>>(cnt, off, cur);
    scatter_edges<<<(E2 + 255) / 256, 256, 0, stream>>>(ei, cur, csr);

    // input projection + relu: h0 = relu(x @ w_in + b_in)   (N,256)->(N,64)
    gemm_tile<256, 64, 64, true, true><<<dim3(NPAD / 64, 1), 256, 0, stream>>>(x, w_in, b_in, h0, NN);

    // GAT layer 0 (in=64)
    gemm_tile<64, 256, 128, false, false><<<dim3(NPAD / 128, 4), 256, 0, stream>>>(h0, lin_w0, nullptr, hh, NN);
    attn_scores<<<NN / 4, 256, 0, stream>>>(hh, att_src, att_dst, ssrc, sdst);
    gat_node<<<NN / 4, 256, 0, stream>>>(hh, ssrc, sdst, csr, off, gbias, conf_w, conf_b, conf, h, 0);

    // GAT layers 1,2 (in=256)
    for (int i = 1; i < 3; i++) {
        gemm_tile<256, 256, 128, false, false><<<dim3(NPAD / 128, 4), 256, 0, stream>>>(
            h, lin_w12 + (size_t)(i - 1) * HC * HC, nullptr, hh, NN);
        attn_scores<<<NN / 4, 256, 0, stream>>>(hh, att_src + i * HHD * CC, att_dst + i * HHD * CC, ssrc, sdst);
        gat_node<<<NN / 4, 256, 0, stream>>>(hh, ssrc, sdst, csr, off, gbias + i * HC, conf_w, conf_b, conf, h, i);
    }

    // heads: T = relu(h @ [nc_w1|oc_w1|ec_w1] + b)   (N,192)
    repack_heads<<<(256 * 192 + 255) / 256, 256, 0, stream>>>(nc_w1, oc_w1, ec_w1, nc_b1, oc_b1, ec_b1, Wcat, bcat);
    gemm_tile<256, 192, 128, true, true><<<dim3(NPAD / 128, 3), 256, 0, stream>>>(h, Wcat, bcat, Tbuf, NN);
    head_final<<<NN / 4, 256, 0, stream>>>(Tbuf, h, nc_w2, nc_b2, oc_w2, oc_b2, ec_w2, ec_b2, out);
}

// Round 3
// 583.943 us; speedup vs baseline: 1.4212x; 1.1698x over previous
//
#include <hip/hip_runtime.h>
#include <cstdint>
#include <cstddef>

#define NN   20000
#define NPAD 20096   // 157*128
#define EE   640000
#define E2   660000   // EE + NN self loops
#define HHD  4
#define CC   64
#define HC   256
#define NEG  0.2f

__device__ __forceinline__ float sigmoidf_(float x) { return 1.0f / (1.0f + __expf(-x)); }

__device__ __forceinline__ float wred_sum(float v) {
#pragma unroll
    for (int d = 32; d; d >>= 1) v += __shfl_xor(v, d, 64);
    return v;
}

__device__ __forceinline__ unsigned short f2bf(float f) {
    unsigned u = __float_as_uint(f);
    u = (u + 0x7fff + ((u >> 16) & 1)) >> 16;   // RNE
    return (unsigned short)u;
}
__device__ __forceinline__ float bf_lo(unsigned u) { return __uint_as_float(u << 16); }
__device__ __forceinline__ float bf_hi(unsigned u) { return __uint_as_float(u & 0xffff0000u); }

// ---------------- CSR build ----------------
__global__ void zero_cnt(int* cnt) {
    int i = blockIdx.x * 256 + threadIdx.x;
    if (i < NN) cnt[i] = 0;
}

__global__ void count_edges(const int* __restrict__ ei, int* __restrict__ cnt) {
    int e = blockIdx.x * 256 + threadIdx.x;
    if (e < E2) {
        int d = (e < EE) ? ei[EE + e] : (e - EE);
        atomicAdd(&cnt[d], 1);
    }
}

// single block, 1024 threads; each thread owns 20 contiguous counts.
__global__ __launch_bounds__(1024) void scan_off(const int* __restrict__ cnt,
                                                 int* __restrict__ off,
                                                 int* __restrict__ cur) {
    __shared__ int buf[1024];
    int t = threadIdx.x;
    int base = t * 20;
    int local[20];
    int s = 0;
#pragma unroll
    for (int i = 0; i < 20; i++) {
        int idx = base + i;
        int v = (idx < NN) ? cnt[idx] : 0;
        local[i] = v;
        s += v;
    }
    buf[t] = s;
    __syncthreads();
    for (int d = 1; d < 1024; d <<= 1) {
        int tv = (t >= d) ? buf[t - d] : 0;
        __syncthreads();
        buf[t] += tv;
        __syncthreads();
    }
    int run = buf[t] - s;  // exclusive prefix of this thread's chunk
#pragma unroll
    for (int i = 0; i < 20; i++) {
        int idx = base + i;
        if (idx < NN) { off[idx] = run; cur[idx] = run; }
        run += local[i];
    }
    if (t == 1023) off[NN] = buf[1023];
}

__global__ void scatter_edges(const int* __restrict__ ei, int* __restrict__ cur,
                              int* __restrict__ csr) {
    int e = blockIdx.x * 256 + threadIdx.x;
    if (e < E2) {
        int s, d;
        if (e < EE) { s = ei[e]; d = ei[EE + e]; }
        else        { s = e - EE; d = s; }
        int p = atomicAdd(&cur[d], 1);
        csr[p] = s;
    }
}

// ---------------- fp32 tiled GEMM: Out[n, OUT] = A[n, IN] @ W[IN, OUT] ----------------
// TM rows x 64 cols per 256-thread block; A and W tiles staged in LDS.
// OBF16: write bf16 output. ATTN: fuse per-head attention scores from fp32 acc
// (blockIdx.y == head when OUT_CH==256).
template <int IN_CH, int OUT_CH, int TM, bool RELU, bool BIAS, bool OBF16, bool ATTN>
__global__ __launch_bounds__(256) void gemm_tile(const float* __restrict__ A,
                                                 const float* __restrict__ W,
                                                 const float* __restrict__ bias,
                                                 float* __restrict__ Outf,
                                                 unsigned short* __restrict__ Outb,
                                                 const float* __restrict__ a_src,
                                                 const float* __restrict__ a_dst,
                                                 float* __restrict__ s_src,
                                                 float* __restrict__ s_dst,
                                                 int nreal) {
    constexpr int R = TM / 16;                  // rows per thread
    __shared__ float As[TM][68];
    __shared__ float Ws[64][68];
    const int tid = threadIdx.x;
    const int tx = tid & 15, tm = tid >> 4;
    const int mb = blockIdx.x * TM;
    const int cb = blockIdx.y * 64;
    const int c0 = cb + tx * 4;

    float acc[R][4];
#pragma unroll
    for (int j = 0; j < R; j++)
#pragma unroll
        for (int q = 0; q < 4; q++) acc[j][q] = 0.0f;

    for (int kc = 0; kc < IN_CH; kc += 64) {
        // stage A tile
#pragma unroll
        for (int i = 0; i < R; i++) {
            int f = tid + i * 256;
            int r = f >> 4;
            int kq = (f & 15) * 4;
            int row = mb + r;
            float4 v = make_float4(0.f, 0.f, 0.f, 0.f);
            if (row < nreal) v = *(const float4*)&A[(size_t)row * IN_CH + kc + kq];
            *(float4*)&As[r][kq] = v;
        }
        // stage W tile
#pragma unroll
        for (int i = 0; i < 4; i++) {
            int f = tid + i * 256;
            int r = f >> 4;
            int wc = (f & 15) * 4;
            *(float4*)&Ws[r][wc] = *(const float4*)&W[(size_t)(kc + r) * OUT_CH + cb + wc];
        }
        __syncthreads();
#pragma unroll 4
        for (int k4 = 0; k4 < 64; k4 += 4) {
            float4 w0 = *(const float4*)&Ws[k4 + 0][tx * 4];
            float4 w1 = *(const float4*)&Ws[k4 + 1][tx * 4];
            float4 w2 = *(const float4*)&Ws[k4 + 2][tx * 4];
            float4 w3 = *(const float4*)&Ws[k4 + 3][tx * 4];
#pragma unroll
            for (int j = 0; j < R; j++) {
                float4 a = *(const float4*)&As[tm * R + j][k4];
                acc[j][0] += a.x * w0.x + a.y * w1.x + a.z * w2.x + a.w * w3.x;
                acc[j][1] += a.x * w0.y + a.y * w1.y + a.z * w2.y + a.w * w3.y;
                acc[j][2] += a.x * w0.z + a.y * w1.z + a.z * w2.z + a.w * w3.z;
                acc[j][3] += a.x * w0.w + a.y * w1.w + a.z * w2.w + a.w * w3.w;
            }
        }
        __syncthreads();
    }

    if (ATTN) {
        // per-row, per-head attention scores from fp32 acc (head = blockIdx.y)
        const float* av = a_src + blockIdx.y * 64 + tx * 4;
        const float* dv = a_dst + blockIdx.y * 64 + tx * 4;
        float4 a4 = *(const float4*)av;
        float4 d4 = *(const float4*)dv;
        float ps[R], pd[R];
#pragma unroll
        for (int j = 0; j < R; j++) {
            ps[j] = acc[j][0] * a4.x + acc[j][1] * a4.y + acc[j][2] * a4.z + acc[j][3] * a4.w;
            pd[j] = acc[j][0] * d4.x + acc[j][1] * d4.y + acc[j][2] * d4.z + acc[j][3] * d4.w;
        }
#pragma unroll
        for (int d = 8; d; d >>= 1) {
#pragma unroll
            for (int j = 0; j < R; j++) {
                ps[j] += __shfl_xor(ps[j], d, 64);
                pd[j] += __shfl_xor(pd[j], d, 64);
            }
        }
        if (tx == 0) {
#pragma unroll
            for (int j = 0; j < R; j++) {
                int row = mb + tm * R + j;
                if (row < nreal) {
                    s_src[row * 4 + blockIdx.y] = ps[j];
                    s_dst[row * 4 + blockIdx.y] = pd[j];
                }
            }
        }
    }

#pragma unroll
    for (int j = 0; j < R; j++) {
        int row = mb + tm * R + j;
        float4 v = make_float4(acc[j][0], acc[j][1], acc[j][2], acc[j][3]);
        if (BIAS) {
            v.x += bias[c0];     v.y += bias[c0 + 1];
            v.z += bias[c0 + 2]; v.w += bias[c0 + 3];
        }
        if (RELU) {
            v.x = fmaxf(v.x, 0.f); v.y = fmaxf(v.y, 0.f);
            v.z = fmaxf(v.z, 0.f); v.w = fmaxf(v.w, 0.f);
        }
        if (OBF16) {
            ushort4 o;
            o.x = f2bf(v.x); o.y = f2bf(v.y); o.z = f2bf(v.z); o.w = f2bf(v.w);
            *(ushort4*)&Outb[(size_t)row * OUT_CH + c0] = o;
        } else {
            *(float4*)&Outf[(size_t)row * OUT_CH + c0] = v;
        }
    }
}

// ---------------- per-dst-node GAT aggregation (one wave per node, 4 nodes/block) ----------------
__global__ __launch_bounds__(256) void gat_node(const unsigned short* __restrict__ hhb,
                                                const float* __restrict__ s_src,
                                                const float* __restrict__ s_dst,
                                                const int* __restrict__ csr_src,
                                                const int* __restrict__ csr_off,
                                                const float* __restrict__ gbias,
                                                const float* __restrict__ conf_w,
                                                const float* __restrict__ conf_b,
                                                const float* __restrict__ confid,
                                                float* __restrict__ h, int layer) {
    int n = blockIdx.x * 4 + (threadIdx.x >> 6);
    int lane = threadIdx.x & 63;
    int off0 = csr_off[n];
    int deg = csr_off[n + 1] - off0;

    float4 sd4 = *(const float4*)&s_dst[n * 4];
    float sdh[4] = {sd4.x, sd4.y, sd4.z, sd4.w};

    // pass 1: per-head max over incoming edges (lane-parallel)
    float mx[4] = {-1e30f, -1e30f, -1e30f, -1e30f};
    for (int e = lane; e < deg; e += 64) {
        int s = csr_src[off0 + e];
        float4 ss = *(const float4*)&s_src[s * 4];
        float a0 = ss.x + sdh[0]; a0 = a0 > 0.f ? a0 : NEG * a0; mx[0] = fmaxf(mx[0], a0);
        float a1 = ss.y + sdh[1]; a1 = a1 > 0.f ? a1 : NEG * a1; mx[1] = fmaxf(mx[1], a1);
        float a2 = ss.z + sdh[2]; a2 = a2 > 0.f ? a2 : NEG * a2; mx[2] = fmaxf(mx[2], a2);
        float a3 = ss.w + sdh[3]; a3 = a3 > 0.f ? a3 : NEG * a3; mx[3] = fmaxf(mx[3], a3);
    }
#pragma unroll
    for (int d = 32; d; d >>= 1) {
#pragma unroll
        for (int hd = 0; hd < 4; hd++) mx[hd] = fmaxf(mx[hd], __shfl_xor(mx[hd], d, 64));
    }

    // pass 2: per-head exp-sum (lane-parallel)
    float sm[4] = {0.f, 0.f, 0.f, 0.f};
    for (int e = lane; e < deg; e += 64) {
        int s = csr_src[off0 + e];
        float4 ss = *(const float4*)&s_src[s * 4];
        float a0 = ss.x + sdh[0]; a0 = a0 > 0.f ? a0 : NEG * a0; sm[0] += __expf(a0 - mx[0]);
        float a1 = ss.y + sdh[1]; a1 = a1 > 0.f ? a1 : NEG * a1; sm[1] += __expf(a1 - mx[1]);
        float a2 = ss.z + sdh[2]; a2 = a2 > 0.f ? a2 : NEG * a2; sm[2] += __expf(a2 - mx[2]);
        float a3 = ss.w + sdh[3]; a3 = a3 > 0.f ? a3 : NEG * a3; sm[3] += __expf(a3 - mx[3]);
    }
#pragma unroll
    for (int d = 32; d; d >>= 1) {
#pragma unroll
        for (int hd = 0; hd < 4; hd++) sm[hd] += __shfl_xor(sm[hd], d, 64);
    }

    int myhead = lane >> 4;
    float sdm = sdh[myhead];
    float mxm = mx[myhead];
    float invm = 1.0f / fmaxf(sm[myhead], 1e-16f);

    // pass 3: weighted bf16 gather-accumulate; lane owns channels 4*lane..4*lane+3.
    // 8x unrolled: 8 independent 8B gather chains in flight.
    const int* cp = csr_src + off0;
    float ax = 0.f, ay = 0.f, az = 0.f, aw = 0.f;
    int e = 0;
    for (; e + 8 <= deg; e += 8) {
        int sidx[8];
        uint2 uv[8];
        float b[8];
#pragma unroll
        for (int q = 0; q < 8; q++) sidx[q] = cp[e + q];
#pragma unroll
        for (int q = 0; q < 8; q++)
            uv[q] = *(const uint2*)&hhb[(size_t)sidx[q] * HC + lane * 4];
#pragma unroll
        for (int q = 0; q < 8; q++) {
            float a = s_src[sidx[q] * 4 + myhead] + sdm;
            a = a > 0.f ? a : NEG * a;
            b[q] = __expf(a - mxm) * invm;
        }
#pragma unroll
        for (int q = 0; q < 8; q++) {
            ax += b[q] * bf_lo(uv[q].x); ay += b[q] * bf_hi(uv[q].x);
            az += b[q] * bf_lo(uv[q].y); aw += b[q] * bf_hi(uv[q].y);
        }
    }
    for (; e < deg; e++) {
        int s = cp[e];
        float a = s_src[s * 4 + myhead] + sdm;
        a = a > 0.f ? a : NEG * a;
        float coef = __expf(a - mxm) * invm;
        uint2 u = *(const uint2*)&hhb[(size_t)s * HC + lane * 4];
        ax += coef * bf_lo(u.x); ay += coef * bf_hi(u.x);
        az += coef * bf_lo(u.y); aw += coef * bf_hi(u.y);
    }

    // epilogue: bias, confidence gate, residual, relu
    float4 b4 = *(const float4*)&gbias[lane * 4];
    float hx = ax + b4.x, hy = ay + b4.y, hz = az + b4.z, hw = aw + b4.w;
    float4 cw4 = *(const float4*)&conf_w[lane * 4];
    float local = hx * cw4.x + hy * cw4.y + hz * cw4.z + hw * cw4.w;
    float tot = wred_sum(local);
    float cw = sigmoidf_(tot + conf_b[0]) * sigmoidf_(confid[n]);
    hx *= cw; hy *= cw; hz *= cw; hw *= cw;
    if (layer > 0) {
        float4 hp = *(const float4*)&h[(size_t)n * HC + lane * 4];
        hx += hp.x; hy += hp.y; hz += hp.z; hw += hp.w;
    }
    if (layer < 2) {
        hx = fmaxf(hx, 0.f); hy = fmaxf(hy, 0.f);
        hz = fmaxf(hz, 0.f); hw = fmaxf(hw, 0.f);
    }
    *(float4*)&h[(size_t)n * HC + lane * 4] = make_float4(hx, hy, hz, hw);
}

// ---------------- pack the 3 head W1/b1 into one (256,192) GEMM ----------------
__global__ void repack_heads(const float* __restrict__ nc1, const float* __restrict__ oc1,
                             const float* __restrict__ ec1, const float* __restrict__ nb,
                             const float* __restrict__ ob, const float* __restrict__ eb,
                             float* __restrict__ Wcat, float* __restrict__ bcat) {
    int idx = blockIdx.x * 256 + threadIdx.x;
    if (idx < 256 * 192) {
        int k = idx / 192, j = idx % 192;
        int g = j >> 6, jj = j & 63;
        const float* w = (g == 0) ? nc1 : ((g == 1) ? oc1 : ec1);
        Wcat[idx] = w[k * 64 + jj];
    }
    if (idx < 192) {
        int g = idx >> 6, jj = idx & 63;
        const float* b = (g == 0) ? nb : ((g == 1) ? ob : eb);
        bcat[idx] = b[jj];
    }
}

// ---------------- final heads + h copy-out ----------------
__global__ __launch_bounds__(256) void head_final(const float* __restrict__ T,
                                                  const float* __restrict__ h,
                                                  const float* __restrict__ nc_w2,
                                                  const float* __restrict__ nc_b2,
                                                  const float* __restrict__ oc_w2,
                                                  const float* __restrict__ oc_b2,
                                                  const float* __restrict__ ec_w2,
                                                  const float* __restrict__ ec_b2,
                                                  float* __restrict__ out) {
    int n = blockIdx.x * 4 + (threadIdx.x >> 6);
    int lane = threadIdx.x & 63;
    float t0 = T[(size_t)n * 192 + lane];
    float t1 = T[(size_t)n * 192 + 64 + lane];
    float t2 = T[(size_t)n * 192 + 128 + lane];
    float pn = wred_sum(t0 * nc_w2[lane]);
    float po = wred_sum(t1 * oc_w2[lane]);
    float4 ew = *(const float4*)&ec_w2[lane * 4];
    float e0 = wred_sum(t2 * ew.x);
    float e1 = wred_sum(t2 * ew.y);
    float e2 = wred_sum(t2 * ew.z);
    float e3 = wred_sum(t2 * ew.w);
    if (lane == 0) {
        out[n] = sigmoidf_(pn + nc_b2[0]);
        out[NN + n] = sigmoidf_(po + oc_b2[0]);
        float4 ev = make_float4(e0 + ec_b2[0], e1 + ec_b2[1], e2 + ec_b2[2], e3 + ec_b2[3]);
        *(float4*)&out[2 * NN + n * 4] = ev;
    }
    float4 hv = *(const float4*)&h[(size_t)n * HC + lane * 4];
    *(float4*)&out[6 * NN + (size_t)n * HC + lane * 4] = hv;
}

extern "C" void kernel_launch(void* const* d_in, const int* in_sizes, int n_in,
                              void* d_out, int out_size, void* d_ws, size_t ws_size,
                              hipStream_t stream) {
    const float* x       = (const float*)d_in[0];
    const int*   ei      = (const int*)d_in[1];
    const float* conf    = (const float*)d_in[2];
    const float* w_in    = (const float*)d_in[3];
    const float* b_in    = (const float*)d_in[4];
    const float* lin_w0  = (const float*)d_in[5];
    const float* lin_w12 = (const float*)d_in[6];
    const float* att_src = (const float*)d_in[7];
    const float* att_dst = (const float*)d_in[8];
    const float* gbias   = (const float*)d_in[9];
    const float* conf_w  = (const float*)d_in[10];
    const float* conf_b  = (const float*)d_in[11];
    const float* nc_w1   = (const float*)d_in[12];
    const float* nc_b1   = (const float*)d_in[13];
    const float* nc_w2   = (const float*)d_in[14];
    const float* nc_b2   = (const float*)d_in[15];
    const float* oc_w1   = (const float*)d_in[16];
    const float* oc_b1   = (const float*)d_in[17];
    const float* oc_w2   = (const float*)d_in[18];
    const float* oc_b2   = (const float*)d_in[19];
    const float* ec_w1   = (const float*)d_in[20];
    const float* ec_b1   = (const float*)d_in[21];
    const float* ec_w2   = (const float*)d_in[22];
    const float* ec_b2   = (const float*)d_in[23];
    float* out = (float*)d_out;

    char* p = (char*)d_ws;
    auto alloc = [&](size_t bytes) -> void* {
        void* r = (void*)p;
        p += (bytes + 255) & ~(size_t)255;
        return r;
    };
    float*          h    = (float*)alloc((size_t)NPAD * HC * 4);
    float*          ssrc = (float*)alloc((size_t)NN * 4 * 4);
    float*          sdst = (float*)alloc((size_t)NN * 4 * 4);
    int*            cnt  = (int*)alloc((size_t)NN * 4);
    int*            off  = (int*)alloc((size_t)(NN + 1) * 4);
    int*            cur  = (int*)alloc((size_t)NN * 4);
    int*            csr  = (int*)alloc((size_t)E2 * 4);
    float*          Wcat = (float*)alloc((size_t)256 * 192 * 4);
    float*          bcat = (float*)alloc((size_t)192 * 4);
    // big scratch: h0 (fp32 N x 64) + hh (bf16 N x 256) live together during the
    // GAT phase; Tbuf (fp32 N x 192) aliases the same region afterwards.
    char*           big  = (char*)alloc((size_t)NPAD * 64 * 4 + (size_t)NPAD * HC * 2);
    float*          h0   = (float*)big;
    unsigned short* hh   = (unsigned short*)(big + (size_t)NPAD * 64 * 4);
    float*          Tbuf = (float*)big;

    // CSR by dst (with self loops appended)
    zero_cnt<<<(NN + 255) / 256, 256, 0, stream>>>(cnt);
    count_edges<<<(E2 + 255) / 256, 256, 0, stream>>>(ei, cnt);
    scan_off<<<1, 1024, 0, stream>>>(cnt, off, cur);
    scatter_edges<<<(E2 + 255) / 256, 256, 0, stream>>>(ei, cur, csr);

    // input projection + relu: h0 = relu(x @ w_in + b_in)   (N,256)->(N,64)
    gemm_tile<256, 64, 64, true, true, false, false><<<dim3(NPAD / 64, 1), 256, 0, stream>>>(
        x, w_in, b_in, h0, nullptr, nullptr, nullptr, nullptr, nullptr, NN);

    // GAT layer 0 (in=64): hh (bf16) + fused attention scores
    gemm_tile<64, 256, 128, false, false, true, true><<<dim3(NPAD / 128, 4), 256, 0, stream>>>(
        h0, lin_w0, nullptr, nullptr, hh, att_src, att_dst, ssrc, sdst, NN);
    gat_node<<<NN / 4, 256, 0, stream>>>(hh, ssrc, sdst, csr, off, gbias, conf_w, conf_b, conf, h, 0);

    // GAT layers 1,2 (in=256)
    for (int i = 1; i < 3; i++) {
        gemm_tile<256, 256, 128, false, false, true, true><<<dim3(NPAD / 128, 4), 256, 0, stream>>>(
            h, lin_w12 + (size_t)(i - 1) * HC * HC, nullptr, nullptr, hh,
            att_src + i * HHD * CC, att_dst + i * HHD * CC, ssrc, sdst, NN);
        gat_node<<<NN / 4, 256, 0, stream>>>(hh, ssrc, sdst, csr, off, gbias + i * HC, conf_w, conf_b, conf, h, i);
    }

    // heads: T = relu(h @ [nc_w1|oc_w1|ec_w1] + b)   (N,192)
    repack_heads<<<(256 * 192 + 255) / 256, 256, 0, stream>>>(nc_w1, oc_w1, ec_w1, nc_b1, oc_b1, ec_b1, Wcat, bcat);
    gemm_tile<256, 192, 128, true, true, false, false><<<dim3(NPAD / 128, 3), 256, 0, stream>>>(
        h, Wcat, bcat, Tbuf, nullptr, nullptr, nullptr, nullptr, nullptr, NN);
    head_final<<<NN / 4, 256, 0, stream>>>(Tbuf, h, nc_w2, nc_b2, oc_w2, oc_b2, ec_w2, ec_b2, out);
}

// Round 5
// 533.079 us; speedup vs baseline: 1.5568x; 1.0954x over previous
//
#include <hip/hip_runtime.h>
#include <cstdint>
#include <cstddef>

#define NN   20000
#define NPAD 20096   // 157*128
#define EE   640000
#define E2   660000   // EE + NN self loops
#define HHD  4
#define CC   64
#define HC   256
#define NEG  0.2f

typedef short bf16x8 __attribute__((ext_vector_type(8)));
typedef float f32x4 __attribute__((ext_vector_type(4)));

__device__ __forceinline__ float sigmoidf_(float x) { return 1.0f / (1.0f + __expf(-x)); }

__device__ __forceinline__ float wred_sum(float v) {
#pragma unroll
    for (int d = 32; d; d >>= 1) v += __shfl_xor(v, d, 64);
    return v;
}

__device__ __forceinline__ unsigned short f2bf(float f) {
    unsigned u = __float_as_uint(f);
    u = (u + 0x7fff + ((u >> 16) & 1)) >> 16;   // RNE
    return (unsigned short)u;
}
__device__ __forceinline__ float bfval(unsigned short h) { return __uint_as_float(((unsigned)h) << 16); }
__device__ __forceinline__ float bf_lo(unsigned u) { return __uint_as_float(u << 16); }
__device__ __forceinline__ float bf_hi(unsigned u) { return __uint_as_float(u & 0xffff0000u); }

// ---------------- CSR build ----------------
__global__ void zero_cnt(int* cnt) {
    int i = blockIdx.x * 256 + threadIdx.x;
    if (i < NN) cnt[i] = 0;
}

__global__ void count_edges(const int* __restrict__ ei, int* __restrict__ cnt) {
    int e = blockIdx.x * 256 + threadIdx.x;
    if (e < E2) {
        int d = (e < EE) ? ei[EE + e] : (e - EE);
        atomicAdd(&cnt[d], 1);
    }
}

__global__ __launch_bounds__(1024) void scan_off(const int* __restrict__ cnt,
                                                 int* __restrict__ off,
                                                 int* __restrict__ cur) {
    __shared__ int buf[1024];
    int t = threadIdx.x;
    int base = t * 20;
    int local[20];
    int s = 0;
#pragma unroll
    for (int i = 0; i < 20; i++) {
        int idx = base + i;
        int v = (idx < NN) ? cnt[idx] : 0;
        local[i] = v;
        s += v;
    }
    buf[t] = s;
    __syncthreads();
    for (int d = 1; d < 1024; d <<= 1) {
        int tv = (t >= d) ? buf[t - d] : 0;
        __syncthreads();
        buf[t] += tv;
        __syncthreads();
    }
    int run = buf[t] - s;
#pragma unroll
    for (int i = 0; i < 20; i++) {
        int idx = base + i;
        if (idx < NN) { off[idx] = run; cur[idx] = run; }
        run += local[i];
    }
    if (t == 1023) off[NN] = buf[1023];
}

__global__ void scatter_edges(const int* __restrict__ ei, int* __restrict__ cur,
                              int* __restrict__ csr) {
    int e = blockIdx.x * 256 + threadIdx.x;
    if (e < E2) {
        int s, d;
        if (e < EE) { s = ei[e]; d = ei[EE + e]; }
        else        { s = e - EE; d = s; }
        int p = atomicAdd(&cur[d], 1);
        csr[p] = s;
    }
}

// ---------------- weight repack: fp32 W[K][N] -> bf16 hi/lo W^T[N][K] ----------------
// segments (flat n-major):   elems        N    K    src
//   wt_in   @ 0              16384        64   256  w_in[k*64+n]
//   wt_l0   @ 16384          16384        256  64   lin_w0[k*256+n]
//   wt_a    @ 32768          65536        256  256  lin_w12[k*256+n]
//   wt_b    @ 98304          65536        256  256  lin_w12[65536+k*256+n]
//   wt_hd   @ 163840         49152        192  256  nc/oc/ec_w1[k*64+(n%64)]
#define WTOT 212992
__global__ void repack_w(const float* __restrict__ w_in, const float* __restrict__ lin_w0,
                         const float* __restrict__ lin_w12,
                         const float* __restrict__ nc1, const float* __restrict__ oc1,
                         const float* __restrict__ ec1,
                         const float* __restrict__ nb, const float* __restrict__ ob,
                         const float* __restrict__ eb,
                         unsigned short* __restrict__ whi, unsigned short* __restrict__ wlo,
                         float* __restrict__ bcat) {
    int idx = blockIdx.x * 256 + threadIdx.x;
    if (idx < 192) {
        int g = idx >> 6, jj = idx & 63;
        const float* b = (g == 0) ? nb : ((g == 1) ? ob : eb);
        bcat[idx] = b[jj];
    }
    if (idx >= WTOT) return;
    float v;
    if (idx < 16384) {
        int n = idx >> 8, k = idx & 255;
        v = w_in[k * 64 + n];
    } else if (idx < 32768) {
        int r = idx - 16384;
        int n = r >> 6, k = r & 63;
        v = lin_w0[k * 256 + n];
    } else if (idx < 98304) {
        int r = idx - 32768;
        int n = r >> 8, k = r & 255;
        v = lin_w12[k * 256 + n];
    } else if (idx < 163840) {
        int r = idx - 98304;
        int n = r >> 8, k = r & 255;
        v = lin_w12[65536 + k * 256 + n];
    } else {
        int r = idx - 163840;
        int n = r >> 8, k = r & 255;
        int g = n >> 6, jj = n & 63;
        const float* w = (g == 0) ? nc1 : ((g == 1) ? oc1 : ec1);
        v = w[k * 64 + jj];
    }
    unsigned short hi = f2bf(v);
    whi[idx] = hi;
    wlo[idx] = f2bf(v - bfval(hi));
}

// ---------------- split-precision bf16 MFMA GEMM ----------------
// Out[n, OUT] = A[n, K] @ W[K, OUT];  W pre-repacked as W^T hi/lo bf16.
// Block: 128 rows x 64 cols, 4 waves, wave tile 32x64 (2 rg x 4 cg of 16x16).
// 3-term split per tile: ah*bh + al*bh + ah*bl  (~fp32 quality).
template <int K, int OUT_CH, bool OBF16, bool ATTN, bool RELUBIAS>
__global__ __launch_bounds__(256) void gemm_mfma(const float* __restrict__ A,
                                                 const unsigned short* __restrict__ Wt_hi,
                                                 const unsigned short* __restrict__ Wt_lo,
                                                 const float* __restrict__ bias,
                                                 float* __restrict__ Outf,
                                                 unsigned short* __restrict__ Outb,
                                                 const float* __restrict__ a_src,
                                                 const float* __restrict__ a_dst,
                                                 float* __restrict__ s_src,
                                                 float* __restrict__ s_dst,
                                                 int nreal) {
    __shared__ unsigned short Ah[128][72], Al[128][72];
    __shared__ unsigned short Bh[64][72], Bl[64][72];
    const int tid = threadIdx.x;
    const int wv = tid >> 6, lane = tid & 63;
    const int quad = lane >> 4, ln = lane & 15;
    const int mb = blockIdx.x * 128;
    const int cb = blockIdx.y * 64;

    f32x4 acc[2][4];
#pragma unroll
    for (int i = 0; i < 2; i++)
#pragma unroll
        for (int j = 0; j < 4; j++) {
            acc[i][j][0] = 0.f; acc[i][j][1] = 0.f;
            acc[i][j][2] = 0.f; acc[i][j][3] = 0.f;
        }

    for (int kc = 0; kc < K; kc += 64) {
        // stage A tile 128x64 fp32 -> hi/lo bf16
#pragma unroll
        for (int i = 0; i < 8; i++) {
            int flat = tid + i * 256;
            int r = flat >> 4, kq = (flat & 15) * 4;
            int row = mb + r;
            float4 v = make_float4(0.f, 0.f, 0.f, 0.f);
            if (row < nreal) v = *(const float4*)&A[(size_t)row * K + kc + kq];
            ushort4 hi, lo;
            hi.x = f2bf(v.x); lo.x = f2bf(v.x - bfval(hi.x));
            hi.y = f2bf(v.y); lo.y = f2bf(v.y - bfval(hi.y));
            hi.z = f2bf(v.z); lo.z = f2bf(v.z - bfval(hi.z));
            hi.w = f2bf(v.w); lo.w = f2bf(v.w - bfval(hi.w));
            *(ushort4*)&Ah[r][kq] = hi;
            *(ushort4*)&Al[r][kq] = lo;
        }
        // stage B tile 64n x 64k (already bf16, transposed). Full coverage:
        // 512 16B-chunks (64 rows x 8 chunks), 2 chunks per thread.
#pragma unroll
        for (int i = 0; i < 2; i++) {
            int flat = tid + i * 256;
            int n = flat >> 3, kq = (flat & 7) * 8;
            *(uint4*)&Bh[n][kq] = *(const uint4*)&Wt_hi[(size_t)(cb + n) * K + kc + kq];
            *(uint4*)&Bl[n][kq] = *(const uint4*)&Wt_lo[(size_t)(cb + n) * K + kc + kq];
        }
        __syncthreads();
#pragma unroll
        for (int ks = 0; ks < 64; ks += 32) {
            const int ko = ks + quad * 8;
            bf16x8 ah0 = *(const bf16x8*)&Ah[wv * 32 + ln][ko];
            bf16x8 ah1 = *(const bf16x8*)&Ah[wv * 32 + 16 + ln][ko];
            bf16x8 al0 = *(const bf16x8*)&Al[wv * 32 + ln][ko];
            bf16x8 al1 = *(const bf16x8*)&Al[wv * 32 + 16 + ln][ko];
#pragma unroll
            for (int cg = 0; cg < 4; cg++) {
                bf16x8 bh = *(const bf16x8*)&Bh[cg * 16 + ln][ko];
                bf16x8 bl = *(const bf16x8*)&Bl[cg * 16 + ln][ko];
                acc[0][cg] = __builtin_amdgcn_mfma_f32_16x16x32_bf16(ah0, bh, acc[0][cg], 0, 0, 0);
                acc[0][cg] = __builtin_amdgcn_mfma_f32_16x16x32_bf16(al0, bh, acc[0][cg], 0, 0, 0);
                acc[0][cg] = __builtin_amdgcn_mfma_f32_16x16x32_bf16(ah0, bl, acc[0][cg], 0, 0, 0);
                acc[1][cg] = __builtin_amdgcn_mfma_f32_16x16x32_bf16(ah1, bh, acc[1][cg], 0, 0, 0);
                acc[1][cg] = __builtin_amdgcn_mfma_f32_16x16x32_bf16(al1, bh, acc[1][cg], 0, 0, 0);
                acc[1][cg] = __builtin_amdgcn_mfma_f32_16x16x32_bf16(ah1, bl, acc[1][cg], 0, 0, 0);
            }
        }
        __syncthreads();
    }

    if (ATTN) {
        // blockIdx.y == head; fused attention scores from fp32 acc (pre-bias h)
        float av[4], dv[4];
#pragma unroll
        for (int cg = 0; cg < 4; cg++) {
            av[cg] = a_src[cb + cg * 16 + ln];
            dv[cg] = a_dst[cb + cg * 16 + ln];
        }
#pragma unroll
        for (int rg = 0; rg < 2; rg++)
#pragma unroll
            for (int reg = 0; reg < 4; reg++) {
                float ps = 0.f, pd = 0.f;
#pragma unroll
                for (int cg = 0; cg < 4; cg++) {
                    float t = acc[rg][cg][reg];
                    ps += t * av[cg];
                    pd += t * dv[cg];
                }
#pragma unroll
                for (int d = 1; d < 16; d <<= 1) {
                    ps += __shfl_xor(ps, d, 64);
                    pd += __shfl_xor(pd, d, 64);
                }
                if (ln == 0) {
                    int row = mb + wv * 32 + rg * 16 + quad * 4 + reg;
                    if (row < nreal) {
                        s_src[row * 4 + blockIdx.y] = ps;
                        s_dst[row * 4 + blockIdx.y] = pd;
                    }
                }
            }
    }

    // D layout: row = quad*4 + reg, col = ln (within 16x16 tile)
#pragma unroll
    for (int rg = 0; rg < 2; rg++)
#pragma unroll
        for (int cg = 0; cg < 4; cg++) {
            int col = cb + cg * 16 + ln;
            int rbase = mb + wv * 32 + rg * 16 + quad * 4;
#pragma unroll
            for (int reg = 0; reg < 4; reg++) {
                float v = acc[rg][cg][reg];
                if (RELUBIAS) { v += bias[col]; v = fmaxf(v, 0.f); }
                int r = rbase + reg;
                if (OBF16) Outb[(size_t)r * OUT_CH + col] = f2bf(v);
                else       Outf[(size_t)r * OUT_CH + col] = v;
            }
        }
}

// ---------------- per-dst-node GAT aggregation (one wave per node, 4 nodes/block) ----------------
__global__ __launch_bounds__(256) void gat_node(const unsigned short* __restrict__ hhb,
                                                const float* __restrict__ s_src,
                                                const float* __restrict__ s_dst,
                                                const int* __restrict__ csr_src,
                                                const int* __restrict__ csr_off,
                                                const float* __restrict__ gbias,
                                                const float* __restrict__ conf_w,
                                                const float* __restrict__ conf_b,
                                                const float* __restrict__ confid,
                                                float* __restrict__ h, int layer) {
    int n = blockIdx.x * 4 + (threadIdx.x >> 6);
    int lane = threadIdx.x & 63;
    int off0 = csr_off[n];
    int deg = csr_off[n + 1] - off0;

    float4 sd4 = *(const float4*)&s_dst[n * 4];
    float sdh[4] = {sd4.x, sd4.y, sd4.z, sd4.w};

    float mx[4] = {-1e30f, -1e30f, -1e30f, -1e30f};
    for (int e = lane; e < deg; e += 64) {
        int s = csr_src[off0 + e];
        float4 ss = *(const float4*)&s_src[s * 4];
        float a0 = ss.x + sdh[0]; a0 = a0 > 0.f ? a0 : NEG * a0; mx[0] = fmaxf(mx[0], a0);
        float a1 = ss.y + sdh[1]; a1 = a1 > 0.f ? a1 : NEG * a1; mx[1] = fmaxf(mx[1], a1);
        float a2 = ss.z + sdh[2]; a2 = a2 > 0.f ? a2 : NEG * a2; mx[2] = fmaxf(mx[2], a2);
        float a3 = ss.w + sdh[3]; a3 = a3 > 0.f ? a3 : NEG * a3; mx[3] = fmaxf(mx[3], a3);
    }
#pragma unroll
    for (int d = 32; d; d >>= 1) {
#pragma unroll
        for (int hd = 0; hd < 4; hd++) mx[hd] = fmaxf(mx[hd], __shfl_xor(mx[hd], d, 64));
    }

    float sm[4] = {0.f, 0.f, 0.f, 0.f};
    for (int e = lane; e < deg; e += 64) {
        int s = csr_src[off0 + e];
        float4 ss = *(const float4*)&s_src[s * 4];
        float a0 = ss.x + sdh[0]; a0 = a0 > 0.f ? a0 : NEG * a0; sm[0] += __expf(a0 - mx[0]);
        float a1 = ss.y + sdh[1]; a1 = a1 > 0.f ? a1 : NEG * a1; sm[1] += __expf(a1 - mx[1]);
        float a2 = ss.z + sdh[2]; a2 = a2 > 0.f ? a2 : NEG * a2; sm[2] += __expf(a2 - mx[2]);
        float a3 = ss.w + sdh[3]; a3 = a3 > 0.f ? a3 : NEG * a3; sm[3] += __expf(a3 - mx[3]);
    }
#pragma unroll
    for (int d = 32; d; d >>= 1) {
#pragma unroll
        for (int hd = 0; hd < 4; hd++) sm[hd] += __shfl_xor(sm[hd], d, 64);
    }

    int myhead = lane >> 4;
    float sdm = sdh[myhead];
    float mxm = mx[myhead];
    float invm = 1.0f / fmaxf(sm[myhead], 1e-16f);

    const int* cp = csr_src + off0;
    float ax = 0.f, ay = 0.f, az = 0.f, aw = 0.f;
    int e = 0;
    for (; e + 8 <= deg; e += 8) {
        int sidx[8];
        uint2 uv[8];
        float b[8];
#pragma unroll
        for (int q = 0; q < 8; q++) sidx[q] = cp[e + q];
#pragma unroll
        for (int q = 0; q < 8; q++)
            uv[q] = *(const uint2*)&hhb[(size_t)sidx[q] * HC + lane * 4];
#pragma unroll
        for (int q = 0; q < 8; q++) {
            float a = s_src[sidx[q] * 4 + myhead] + sdm;
            a = a > 0.f ? a : NEG * a;
            b[q] = __expf(a - mxm) * invm;
        }
#pragma unroll
        for (int q = 0; q < 8; q++) {
            ax += b[q] * bf_lo(uv[q].x); ay += b[q] * bf_hi(uv[q].x);
            az += b[q] * bf_lo(uv[q].y); aw += b[q] * bf_hi(uv[q].y);
        }
    }
    for (; e < deg; e++) {
        int s = cp[e];
        float a = s_src[s * 4 + myhead] + sdm;
        a = a > 0.f ? a : NEG * a;
        float coef = __expf(a - mxm) * invm;
        uint2 u = *(const uint2*)&hhb[(size_t)s * HC + lane * 4];
        ax += coef * bf_lo(u.x); ay += coef * bf_hi(u.x);
        az += coef * bf_lo(u.y); aw += coef * bf_hi(u.y);
    }

    float4 b4 = *(const float4*)&gbias[lane * 4];
    float hx = ax + b4.x, hy = ay + b4.y, hz = az + b4.z, hw = aw + b4.w;
    float4 cw4 = *(const float4*)&conf_w[lane * 4];
    float local = hx * cw4.x + hy * cw4.y + hz * cw4.z + hw * cw4.w;
    float tot = wred_sum(local);
    float cw = sigmoidf_(tot + conf_b[0]) * sigmoidf_(confid[n]);
    hx *= cw; hy *= cw; hz *= cw; hw *= cw;
    if (layer > 0) {
        float4 hp = *(const float4*)&h[(size_t)n * HC + lane * 4];
        hx += hp.x; hy += hp.y; hz += hp.z; hw += hp.w;
    }
    if (layer < 2) {
        hx = fmaxf(hx, 0.f); hy = fmaxf(hy, 0.f);
        hz = fmaxf(hz, 0.f); hw = fmaxf(hw, 0.f);
    }
    *(float4*)&h[(size_t)n * HC + lane * 4] = make_float4(hx, hy, hz, hw);
}

// ---------------- final heads + h copy-out ----------------
__global__ __launch_bounds__(256) void head_final(const float* __restrict__ T,
                                                  const float* __restrict__ h,
                                                  const float* __restrict__ nc_w2,
                                                  const float* __restrict__ nc_b2,
                                                  const float* __restrict__ oc_w2,
                                                  const float* __restrict__ oc_b2,
                                                  const float* __restrict__ ec_w2,
                                                  const float* __restrict__ ec_b2,
                                                  float* __restrict__ out) {
    int n = blockIdx.x * 4 + (threadIdx.x >> 6);
    int lane = threadIdx.x & 63;
    float t0 = T[(size_t)n * 192 + lane];
    float t1 = T[(size_t)n * 192 + 64 + lane];
    float t2 = T[(size_t)n * 192 + 128 + lane];
    float pn = wred_sum(t0 * nc_w2[lane]);
    float po = wred_sum(t1 * oc_w2[lane]);
    float4 ew = *(const float4*)&ec_w2[lane * 4];
    float e0 = wred_sum(t2 * ew.x);
    float e1 = wred_sum(t2 * ew.y);
    float e2 = wred_sum(t2 * ew.z);
    float e3 = wred_sum(t2 * ew.w);
    if (lane == 0) {
        out[n] = sigmoidf_(pn + nc_b2[0]);
        out[NN + n] = sigmoidf_(po + oc_b2[0]);
        float4 ev = make_float4(e0 + ec_b2[0], e1 + ec_b2[1], e2 + ec_b2[2], e3 + ec_b2[3]);
        *(float4*)&out[2 * NN + n * 4] = ev;
    }
    float4 hv = *(const float4*)&h[(size_t)n * HC + lane * 4];
    *(float4*)&out[6 * NN + (size_t)n * HC + lane * 4] = hv;
}

extern "C" void kernel_launch(void* const* d_in, const int* in_sizes, int n_in,
                              void* d_out, int out_size, void* d_ws, size_t ws_size,
                              hipStream_t stream) {
    const float* x       = (const float*)d_in[0];
    const int*   ei      = (const int*)d_in[1];
    const float* conf    = (const float*)d_in[2];
    const float* w_in    = (const float*)d_in[3];
    const float* b_in    = (const float*)d_in[4];
    const float* lin_w0  = (const float*)d_in[5];
    const float* lin_w12 = (const float*)d_in[6];
    const float* att_src = (const float*)d_in[7];
    const float* att_dst = (const float*)d_in[8];
    const float* gbias   = (const float*)d_in[9];
    const float* conf_w  = (const float*)d_in[10];
    const float* conf_b  = (const float*)d_in[11];
    const float* nc_w1   = (const float*)d_in[12];
    const float* nc_b1   = (const float*)d_in[13];
    const float* nc_w2   = (const float*)d_in[14];
    const float* nc_b2   = (const float*)d_in[15];
    const float* oc_w1   = (const float*)d_in[16];
    const float* oc_b1   = (const float*)d_in[17];
    const float* oc_w2   = (const float*)d_in[18];
    const float* oc_b2   = (const float*)d_in[19];
    const float* ec_w1   = (const float*)d_in[20];
    const float* ec_b1   = (const float*)d_in[21];
    const float* ec_w2   = (const float*)d_in[22];
    const float* ec_b2   = (const float*)d_in[23];
    float* out = (float*)d_out;

    char* p = (char*)d_ws;
    auto alloc = [&](size_t bytes) -> void* {
        void* r = (void*)p;
        p += (bytes + 255) & ~(size_t)255;
        return r;
    };
    float*          h    = (float*)alloc((size_t)NPAD * HC * 4);
    float*          ssrc = (float*)alloc((size_t)NN * 4 * 4);
    float*          sdst = (float*)alloc((size_t)NN * 4 * 4);
    int*            cnt  = (int*)alloc((size_t)NN * 4);
    int*            off  = (int*)alloc((size_t)(NN + 1) * 4);
    int*            cur  = (int*)alloc((size_t)NN * 4);
    int*            csr  = (int*)alloc((size_t)E2 * 4);
    unsigned short* whi  = (unsigned short*)alloc((size_t)WTOT * 2);
    unsigned short* wlo  = (unsigned short*)alloc((size_t)WTOT * 2);
    float*          bcat = (float*)alloc((size_t)192 * 4);
    // big scratch: h0 (fp32 N x 64) + hh (bf16 N x 256) live together during the
    // GAT phase; Tbuf (fp32 N x 192) aliases the same region afterwards.
    char*           big  = (char*)alloc((size_t)NPAD * 64 * 4 + (size_t)NPAD * HC * 2);
    float*          h0   = (float*)big;
    unsigned short* hh   = (unsigned short*)(big + (size_t)NPAD * 64 * 4);
    float*          Tbuf = (float*)big;

    const unsigned short* wt_in = whi;            const unsigned short* wt_in_l = wlo;
    const unsigned short* wt_l0 = whi + 16384;    const unsigned short* wt_l0_l = wlo + 16384;
    const unsigned short* wt_a  = whi + 32768;    const unsigned short* wt_a_l  = wlo + 32768;
    const unsigned short* wt_b  = whi + 98304;    const unsigned short* wt_b_l  = wlo + 98304;
    const unsigned short* wt_hd = whi + 163840;   const unsigned short* wt_hd_l = wlo + 163840;

    // CSR by dst (with self loops appended)
    zero_cnt<<<(NN + 255) / 256, 256, 0, stream>>>(cnt);
    count_edges<<<(E2 + 255) / 256, 256, 0, stream>>>(ei, cnt);
    scan_off<<<1, 1024, 0, stream>>>(cnt, off, cur);
    scatter_edges<<<(E2 + 255) / 256, 256, 0, stream>>>(ei, cur, csr);

    // weight repack (hi/lo bf16, transposed)
    repack_w<<<(WTOT + 255) / 256, 256, 0, stream>>>(w_in, lin_w0, lin_w12, nc_w1, oc_w1, ec_w1,
                                                     nc_b1, oc_b1, ec_b1, whi, wlo, bcat);

    // input projection + relu: h0 = relu(x @ w_in + b_in)   (N,256)->(N,64)
    gemm_mfma<256, 64, false, false, true><<<dim3(NPAD / 128, 1), 256, 0, stream>>>(
        x, wt_in, wt_in_l, b_in, h0, nullptr, nullptr, nullptr, nullptr, nullptr, NN);

    // GAT layer 0 (in=64): hh (bf16) + fused attention scores
    gemm_mfma<64, 256, true, true, false><<<dim3(NPAD / 128, 4), 256, 0, stream>>>(
        h0, wt_l0, wt_l0_l, nullptr, nullptr, hh, att_src, att_dst, ssrc, sdst, NN);
    gat_node<<<NN / 4, 256, 0, stream>>>(hh, ssrc, sdst, csr, off, gbias, conf_w, conf_b, conf, h, 0);

    // GAT layers 1,2 (in=256)
    for (int i = 1; i < 3; i++) {
        const unsigned short* wh = (i == 1) ? wt_a : wt_b;
        const unsigned short* wl = (i == 1) ? wt_a_l : wt_b_l;
        gemm_mfma<256, 256, true, true, false><<<dim3(NPAD / 128, 4), 256, 0, stream>>>(
            h, wh, wl, nullptr, nullptr, hh,
            att_src + i * HHD * CC, att_dst + i * HHD * CC, ssrc, sdst, NN);
        gat_node<<<NN / 4, 256, 0, stream>>>(hh, ssrc, sdst, csr, off, gbias + i * HC, conf_w, conf_b, conf, h, i);
    }

    // heads: T = relu(h @ [nc_w1|oc_w1|ec_w1] + b)   (N,192)
    gemm_mfma<256, 192, false, false, true><<<dim3(NPAD / 128, 3), 256, 0, stream>>>(
        h, wt_hd, wt_hd_l, bcat, Tbuf, nullptr, nullptr, nullptr, nullptr, nullptr, NN);
    head_final<<<NN / 4, 256, 0, stream>>>(Tbuf, h, nc_w2, nc_b2, oc_w2, oc_b2, ec_w2, ec_b2, out);
}